// Round 8
// baseline (350.202 us; speedup 1.0000x reference)
//
#include <hip/hip_runtime.h>

#define B_ 2
#define V_ 8
#define C_ 32
#define H_ 256
#define W_ 320
#define HW_ (H_ * W_)
#define TPB_ 1024
#define BLK_X_ (HW_ / TPB_)   // 80 blocks per view

__global__ __launch_bounds__(TPB_, 8) void feature_projector_kernel(
    const float* __restrict__ features,     // (B,V,C,H,W)
    const float* __restrict__ projections,  // (B,V,4,4)
    const float* __restrict__ depth,        // (B, H*W)
    float* __restrict__ out)                // (B,V,C,H,W)
{
    const int n = blockIdx.y;                 // view index (uniform per block)
    const int b = n >> 3;                     // V_ == 8

    // XCD swizzle: 80 = 8*10 -> each XCD gets a contiguous 10-block band/view.
    const int bidx = (blockIdx.x & 7) * (BLK_X_ / 8) + (blockIdx.x >> 3);
    const int pix = bidx * TPB_ + threadIdx.x;   // always < HW_ (80*1024 exact)

    const int xi = pix % W_;
    const int yi = pix / W_;
    const float xf = (float)xi;
    const float yf = (float)yi;

    const float* P = projections + n * 16;
    const float r00 = P[0], r01 = P[1], r02 = P[2],  t0 = P[3];
    const float r10 = P[4], r11 = P[5], r12 = P[6],  t1 = P[7];
    const float r20 = P[8], r21 = P[9], r22 = P[10], t2 = P[11];

    const float d = depth[b * HW_ + pix];

    const float cx = (r00 * xf + r01 * yf + r02) * d + t0;
    const float cy = (r10 * xf + r11 * yf + r12) * d + t1;
    const float cz = (r20 * xf + r21 * yf + r22) * d + t2;

    const float px = cx / cz;
    const float py = cy / cz;
    const float gx = px / (float)(W_ - 1) * 2.0f - 1.0f;
    const float gy = py / (float)(H_ - 1) * 2.0f - 1.0f;

    const float ix = (gx + 1.0f) * ((float)W_ * 0.5f) - 0.5f;
    const float iy = (gy + 1.0f) * ((float)H_ * 0.5f) - 0.5f;

    const float ix0 = floorf(ix);
    const float iy0 = floorf(iy);
    const float ix1 = ix0 + 1.0f;
    const float iy1 = iy0 + 1.0f;

    const float wx1 = ix - ix0;
    const float wy1 = iy - iy0;
    const float wx0 = 1.0f - wx1;
    const float wy0 = 1.0f - wy1;

    const float fW1 = (float)(W_ - 1);
    const float fH1 = (float)(H_ - 1);

    // Validity (NaN-safe: comparisons with NaN are false)
    const float vx0 = (ix0 >= 0.0f && ix0 <= fW1) ? 1.0f : 0.0f;
    const float vx1 = (ix1 >= 0.0f && ix1 <= fW1) ? 1.0f : 0.0f;
    const float vy0 = (iy0 >= 0.0f && iy0 <= fH1) ? 1.0f : 0.0f;
    const float vy1 = (iy1 >= 0.0f && iy1 <= fH1) ? 1.0f : 0.0f;

    // Clamp in float BEFORE int conversion (NaN -> 0 via fmaxf)
    const int xb  = (int)fminf(fmaxf(ix0, 0.0f), (float)(W_ - 2));
    const int x0c = (int)fminf(fmaxf(ix0, 0.0f), fW1);
    const int x1c = (int)fminf(fmaxf(ix1, 0.0f), fW1);
    const int y0c = (int)fminf(fmaxf(iy0, 0.0f), fH1);
    const int y1c = (int)fminf(fmaxf(iy1, 0.0f), fH1);

    const float wxa = wx0 * vx0;
    const float wxb = wx1 * vx1;
    // Redistribute x-weights onto the fetched pair [xb, xb+1] (all clamp/NaN
    // cases covered; NaN weight propagates like the reference).
    const float a0 = (x0c == xb     ? wxa : 0.0f) + (x1c == xb     ? wxb : 0.0f);
    const float a1 = (x0c == xb + 1 ? wxa : 0.0f) + (x1c == xb + 1 ? wxb : 0.0f);
    const float ry0 = wy0 * vy0;
    const float ry1 = wy1 * vy1;

    const int r0 = y0c * W_ + xb;
    const int r1 = y1c * W_ + xb;

    const float* __restrict__ fN = features + (size_t)n * C_ * HW_;
    float* __restrict__ oN = out + (size_t)n * C_ * HW_ + pix;

    // Channel-OUTER sweep, 2-deep pipeline, raw s_barrier pacing so all 16
    // waves stay on the same channel (per-channel block footprint ~8 KB fits
    // L1 -> y-adjacent row taps are L1 hits instead of L2 line requests).
    // s_barrier without waitcnt is safe: zero inter-thread data deps.
    float2 qa0, qa1, qb0, qb1;

#define LOADC(d0, d1, c)                                                 \
    {                                                                    \
        const float* __restrict__ fc = fN + (size_t)(c) * HW_;           \
        __builtin_memcpy(&d0, fc + r0, 8);                               \
        __builtin_memcpy(&d1, fc + r1, 8);                               \
    }
#define COMPC(s0, s1, c)                                                 \
    {                                                                    \
        const float v = (s0.x * a0 + s0.y * a1) * ry0                    \
                      + (s1.x * a0 + s1.y * a1) * ry1;                   \
        __builtin_nontemporal_store(v, &oN[(size_t)(c) * HW_]);          \
    }

    LOADC(qa0, qa1, 0)
    LOADC(qb0, qb1, 1)
    __builtin_amdgcn_sched_barrier(0);

#pragma unroll 1
    for (int c = 0; c < C_ - 2; c += 2) {
        __builtin_amdgcn_s_barrier();      // pacing only (no data exchange)
        COMPC(qa0, qa1, c)
        LOADC(qa0, qa1, c + 2)
        __builtin_amdgcn_sched_barrier(0);
        COMPC(qb0, qb1, c + 1)
        LOADC(qb0, qb1, c + 3)
        __builtin_amdgcn_sched_barrier(0);
    }
    COMPC(qa0, qa1, C_ - 2)
    COMPC(qb0, qb1, C_ - 1)

#undef LOADC
#undef COMPC
}

extern "C" void kernel_launch(void* const* d_in, const int* in_sizes, int n_in,
                              void* d_out, int out_size, void* d_ws, size_t ws_size,
                              hipStream_t stream) {
    const float* features    = (const float*)d_in[0];
    const float* projections = (const float*)d_in[1];
    const float* depth       = (const float*)d_in[2];
    float* out = (float*)d_out;

    dim3 block(TPB_, 1, 1);
    dim3 grid(BLK_X_, B_ * V_, 1);
    feature_projector_kernel<<<grid, block, 0, stream>>>(features, projections, depth, out);
}